// Round 12
// baseline (205.380 us; speedup 1.0000x reference)
//
#include <hip/hip_runtime.h>
#include <math.h>

#define B_    2
#define L_    2048
#define D_    1024
#define H_    16
#define HD_   64
#define HALF_ 128
#define TQ    32          // queries per attention block
#define PST   296         // bf16 P-slab row stride (shorts); 16B-aligned, bank-tiled

typedef __attribute__((ext_vector_type(8))) short short8;
typedef __attribute__((ext_vector_type(4))) float f32x4;

// ---- bf16 helpers (bitwise, RNE) -----------------------------------------
__device__ __forceinline__ unsigned short f2bf(float x) {
  unsigned int u = __float_as_uint(x);
  u = (u + 0x7fffu + ((u >> 16) & 1u)) >> 16;
  return (unsigned short)u;
}
__device__ __forceinline__ float bf2f(unsigned short b) {
  return __uint_as_float(((unsigned int)b) << 16);
}
__device__ __forceinline__ void split1(float a, unsigned short& h, unsigned short& l) {
  h = f2bf(a);
  l = f2bf(a - bf2f(h));
}

__device__ __forceinline__ void async_cp16(const unsigned short* g, unsigned short* l) {
  __builtin_amdgcn_global_load_lds(
      (const __attribute__((address_space(1))) unsigned int*)g,
      (__attribute__((address_space(3))) unsigned int*)l, 16, 0, 0);
}

// ---------------------------------------------------------------------------
// prep: fused (a) x -> hi/lo bf16 split, (b) w_qkv transpose+round,
//       (c) w_out transpose+round.  Branch is block-uniform.
// ---------------------------------------------------------------------------
__device__ __forceinline__ void tr_round32(const float* __restrict__ in,
                                           unsigned short* __restrict__ hi,
                                           int N, int K, int n0, int k0,
                                           float (*t)[33], int tid) {
  {
    const int kl = tid >> 3, nl = (tid & 7) * 4;
    const float4 v = *(const float4*)&in[(size_t)(k0 + kl) * N + n0 + nl];
    t[kl][nl + 0] = v.x; t[kl][nl + 1] = v.y;
    t[kl][nl + 2] = v.z; t[kl][nl + 3] = v.w;
  }
  __syncthreads();
  {
    const int no = tid >> 3, ko = (tid & 7) * 4;
    ushort4 h;
    h.x = f2bf(t[ko + 0][no]);
    h.y = f2bf(t[ko + 1][no]);
    h.z = f2bf(t[ko + 2][no]);
    h.w = f2bf(t[ko + 3][no]);
    *(ushort4*)&hi[(size_t)(n0 + no) * K + k0 + ko] = h;
  }
}

__global__ __launch_bounds__(256) void prep(const float* __restrict__ x,
                                            unsigned short* __restrict__ x_hi,
                                            unsigned short* __restrict__ x_lo,
                                            const float* __restrict__ w_qkv,
                                            unsigned short* __restrict__ wqkvT,
                                            const float* __restrict__ w_out,
                                            unsigned short* __restrict__ woutT) {
  __shared__ float t[32][33];
  const int bx = blockIdx.x, tid = threadIdx.x;
  if (bx < 4096) {
    const int i = (bx * 256 + tid) * 4;
    const float4 a = *(const float4*)&x[i];
    ushort4 h, l;
    split1(a.x, h.x, l.x);
    split1(a.y, h.y, l.y);
    split1(a.z, h.z, l.z);
    split1(a.w, h.w, l.w);
    *(ushort4*)&x_hi[i] = h;
    *(ushort4*)&x_lo[i] = l;
  } else if (bx < 7168) {
    const int tb = bx - 4096;  // 96 x 32 tiles
    tr_round32(w_qkv, wqkvT, 3 * D_, D_, (tb % 96) * 32, (tb / 96) * 32, t, tid);
  } else {
    const int tb = bx - 7168;  // 32 x 32 tiles
    tr_round32(w_out, woutT, D_, D_, (tb % 32) * 32, (tb / 32) * 32, t, tid);
  }
}

// ---------------------------------------------------------------------------
// gemm_qk: SINGLE-product bf16 MFMA GEMM for the Q,K projection slice.
// C = Ah @ Bh^T + bias over N=2048 (q|k columns). Q,K outputs are consumed
// as bf16-hi only (r9 proved the al-product is below the storage quantum).
// 128x128 tile, BK=32, 16 KB LDS (Ah|Bh), staging balanced: each of the 4
// waves stages 4 async_cp16. Branch-free K-loop.
// Epilogue: q -> q_hi[B*L,1024]; k -> kT[b][h][dg8][j2048][8d].
// ---------------------------------------------------------------------------
__global__ __launch_bounds__(256) void gemm_qk(const unsigned short* __restrict__ Ah,
                                               const unsigned short* __restrict__ Bh,
                                               const float* __restrict__ bias,
                                               unsigned short* __restrict__ q_hi,
                                               unsigned short* __restrict__ kT,
                                               int N, int K) {
  __shared__ unsigned short sm[2 * 4096];  // 16 KB: Ah | Bh
  const int tid  = threadIdx.x;
  const int wave = tid >> 6, lane = tid & 63;
  const int m0 = blockIdx.y * 128, n0 = blockIdx.x * 128;
  const int wm = (wave >> 1) * 64, wn = (wave & 1) * 64;
  const int quad = lane >> 4, ln16 = lane & 15;

  // staging: waves 0,1 -> Ah halves; waves 2,3 -> Bh halves (4 insts each)
  const unsigned short* src = (wave < 2) ? Ah : Bh;
  const int baserow = (wave < 2) ? m0 : n0;
  const int io = (wave & 1) * 4;
  size_t goff[4];
#pragma unroll
  for (int i = 0; i < 4; ++i) {
    const int inst = io + i;
    const int r = inst * 16 + (lane >> 2);
    const int q = (lane & 3) ^ ((r >> 1) & 3);
    goff[i] = (size_t)(baserow + r) * K + q * 8;
  }
  unsigned short* dst0 = &sm[(wave >> 1) * 4096 + io * 512];  // io*1024 bytes

  int offA[4], offB[4];
#pragma unroll
  for (int t = 0; t < 4; ++t) {
    const int r = wm + t * 16 + ln16;
    offA[t] = r * 64 + ((quad ^ ((r >> 1) & 3)) * 16);
    const int rn = wn + t * 16 + ln16;
    offB[t] = rn * 64 + ((quad ^ ((rn >> 1) & 3)) * 16);
  }

  f32x4 acc[4][4] = {};
  const char* smb = (const char*)sm;

  for (int k0 = 0; k0 < K; k0 += 32) {
#pragma unroll
    for (int i = 0; i < 4; ++i)
      async_cp16(src + goff[i] + k0,
                 (unsigned short*)((char*)dst0 + i * 1024));
    __syncthreads();

    short8 ah[4], bh[4];
#pragma unroll
    for (int t = 0; t < 4; ++t) {
      ah[t] = *(const short8*)(smb + offA[t]);
      bh[t] = *(const short8*)(smb + 8192 + offB[t]);
    }
#pragma unroll
    for (int t = 0; t < 4; ++t)
#pragma unroll
      for (int u = 0; u < 4; ++u)
        acc[t][u] = __builtin_amdgcn_mfma_f32_16x16x32_bf16(ah[t], bh[u], acc[t][u], 0, 0, 0);
    __syncthreads();
  }

#pragma unroll
  for (int u = 0; u < 4; ++u) {
    const int col = n0 + wn + u * 16 + ln16;
    const float bv = bias[col];
    const int slot = col >> 10;   // 0=q, 1=k (wave-uniform per u-tile)
    const int hd   = col & 1023;
    const int hh_  = hd >> 6;
    const int dg   = (hd & 63) >> 3, di = hd & 7;
#pragma unroll
    for (int t = 0; t < 4; ++t) {
      const int row0 = m0 + wm + t * 16 + quad * 4;
      if (slot == 0) {
#pragma unroll
        for (int e = 0; e < 4; ++e)
          q_hi[(size_t)(row0 + e) * 1024 + hd] = f2bf(acc[t][u][e] + bv);
      } else {
#pragma unroll
        for (int e = 0; e < 4; ++e) {
          const int tok = row0 + e;
          const int bb = tok >> 11, j = tok & 2047;
          const size_t o =
              ((((size_t)bb * 16 + hh_) * 8 + dg) * 2048 + j) * 8 + di;
          kT[o] = f2bf(acc[t][u][e] + bv);
        }
      }
    }
  }
}

// ---------------------------------------------------------------------------
// gemm_n64: 2-product split-bf16 GEMM, 128x64 tile, BK=32, 20 KB LDS,
// 512 blocks (2/CU). EPI=0: fp32 C (out-projection). EPI=1: vTile epilogue
// (V projection slice) -> vTile[b][jg256][d1024][8j].
// ---------------------------------------------------------------------------
template <int EPI>
__global__ __launch_bounds__(256) void gemm_n64(const unsigned short* __restrict__ Ah,
                                                const unsigned short* __restrict__ Al,
                                                const unsigned short* __restrict__ Bh,
                                                const float* __restrict__ bias,
                                                float* __restrict__ C,
                                                unsigned short* __restrict__ vTile,
                                                int N, int K) {
  __shared__ unsigned short sm[2 * 4096 + 2048];  // 20 KB: Ah | Al | Bh
  const int tid  = threadIdx.x;
  const int wave = tid >> 6, lane = tid & 63;
  const int m0 = blockIdx.y * 128, n0 = blockIdx.x * 64;
  const int quad = lane >> 4, ln16 = lane & 15;
  const int wm = wave * 32;

  const unsigned short* src = (wave == 0) ? Ah : (wave == 1) ? Al : Bh;
  const int baserow = (wave < 2) ? m0 : n0;
  size_t goff[8];
#pragma unroll
  for (int inst = 0; inst < 8; ++inst) {
    const int r = inst * 16 + (lane >> 2);
    const int q = (lane & 3) ^ ((r >> 1) & 3);
    goff[inst] = (size_t)(baserow + r) * K + q * 8;
  }
  unsigned short* dst0 = &sm[(wave < 2 ? wave : 2) * 4096];

  int offA[2], offB[4];
#pragma unroll
  for (int t = 0; t < 2; ++t) {
    const int r = wm + t * 16 + ln16;
    offA[t] = r * 64 + ((quad ^ ((r >> 1) & 3)) * 16);
  }
#pragma unroll
  for (int u = 0; u < 4; ++u) {
    const int rn = u * 16 + ln16;
    offB[u] = rn * 64 + ((quad ^ ((rn >> 1) & 3)) * 16);
  }

  f32x4 acc[2][4] = {};
  const char* smb = (const char*)sm;

  for (int k0 = 0; k0 < K; k0 += 32) {
    if (wave < 2) {
#pragma unroll
      for (int inst = 0; inst < 8; ++inst)
        async_cp16(src + goff[inst] + k0,
                   (unsigned short*)((char*)dst0 + inst * 1024));
    } else if (wave == 2) {
#pragma unroll
      for (int inst = 0; inst < 4; ++inst)
        async_cp16(src + goff[inst] + k0,
                   (unsigned short*)((char*)dst0 + inst * 1024));
    }
    __syncthreads();

    short8 ah[2], al[2], bh[4];
#pragma unroll
    for (int t = 0; t < 2; ++t) {
      ah[t] = *(const short8*)(smb + offA[t]);
      al[t] = *(const short8*)(smb + 8192 + offA[t]);
    }
#pragma unroll
    for (int u = 0; u < 4; ++u) bh[u] = *(const short8*)(smb + 16384 + offB[u]);
#pragma unroll
    for (int t = 0; t < 2; ++t)
#pragma unroll
      for (int u = 0; u < 4; ++u) {
        acc[t][u] = __builtin_amdgcn_mfma_f32_16x16x32_bf16(ah[t], bh[u], acc[t][u], 0, 0, 0);
        acc[t][u] = __builtin_amdgcn_mfma_f32_16x16x32_bf16(al[t], bh[u], acc[t][u], 0, 0, 0);
      }
    __syncthreads();
  }

#pragma unroll
  for (int u = 0; u < 4; ++u) {
    const int col = n0 + u * 16 + ln16;
    const float bv = bias[col];
#pragma unroll
    for (int t = 0; t < 2; ++t) {
      const int row0 = m0 + wm + t * 16 + quad * 4;
      if (EPI == 0) {
#pragma unroll
        for (int e = 0; e < 4; ++e)
          C[(size_t)(row0 + e) * N + col] = acc[t][u][e] + bv;
      } else {
        const int bb = row0 >> 11, l0 = row0 & 2047;
        ushort4 vh;
        vh.x = f2bf(acc[t][u][0] + bv);
        vh.y = f2bf(acc[t][u][1] + bv);
        vh.z = f2bf(acc[t][u][2] + bv);
        vh.w = f2bf(acc[t][u][3] + bv);
        const size_t o =
            (((size_t)bb * 256 + (l0 >> 3)) * 1024 + col) * 8 + (l0 & 7);
        *(ushort4*)&vTile[o] = vh;
      }
    }
  }
}

// ---------------------------------------------------------------------------
// MFMA sliding-window attention (unchanged from r11).
// ---------------------------------------------------------------------------
__global__ __launch_bounds__(256, 4) void attn_mfma(
    const unsigned short* __restrict__ q_hi,
    const unsigned short* __restrict__ kT,
    const unsigned short* __restrict__ vTile,
    unsigned short* __restrict__ attn_h,
    unsigned short* __restrict__ attn_l) {
  __shared__ unsigned short P[TQ * PST];  // 18944 B (epilogue reuses as fp32)
  __shared__ float redS[2][32];

  const int b   = blockIdx.z;
  const int h   = blockIdx.y;
  const int i0  = blockIdx.x * TQ;
  const int tid = threadIdx.x;
  const int wave = tid >> 6, lane = tid & 63;
  const int quad = lane >> 4, ln16 = lane & 15;
  const int mt = wave >> 1, np = wave & 1;
  const int jlo = i0 - HALF_;
  const int rbase = mt * 16 + quad * 4;

  // ---- phase 1: scores -> exp -> P(bf16, unnormalized) + row sums --------
  float s[4] = {0.f, 0.f, 0.f, 0.f};
  {
    const size_t qbase =
        (size_t)(b * L_ + i0 + mt * 16 + ln16) * 1024 + h * 64 + quad * 8;
    const short8 qh0 = *(const short8*)&q_hi[qbase];
    const short8 qh1 = *(const short8*)&q_hi[qbase + 32];

    const size_t kb0 = (((size_t)b * 16 + h) * 8 + quad) * 2048 * 8;
    const size_t kb1 = (((size_t)b * 16 + h) * 8 + quad + 4) * 2048 * 8;

#pragma unroll
    for (int c = 0; c < 9; ++c) {
      const int nt   = np + 2 * c;
      const int jabs = jlo + nt * 16 + ln16;
      const int jcl  = min(max(jabs, 0), L_ - 1);
      const short8 kh0 = *(const short8*)&kT[kb0 + (size_t)jcl * 8];
      const short8 kh1 = *(const short8*)&kT[kb1 + (size_t)jcl * 8];

      f32x4 a = {};
      a = __builtin_amdgcn_mfma_f32_16x16x32_bf16(qh0, kh0, a, 0, 0, 0);
      a = __builtin_amdgcn_mfma_f32_16x16x32_bf16(qh1, kh1, a, 0, 0, 0);

      const int colj = nt * 16 + ln16;
#pragma unroll
      for (int e = 0; e < 4; ++e) {
        const int iabs = i0 + rbase + e;
        const bool ok = (jabs >= 0) && (jabs < L_) && (abs(iabs - jabs) <= HALF_);
        const float ev = ok ? __expf(a[e] * 0.125f) : 0.f;
        s[e] += ev;
        P[(rbase + e) * PST + colj] = f2bf(ev);
      }
    }
  }
#pragma unroll
  for (int e = 0; e < 4; ++e) {
    s[e] += __shfl_xor(s[e], 1);
    s[e] += __shfl_xor(s[e], 2);
    s[e] += __shfl_xor(s[e], 4);
    s[e] += __shfl_xor(s[e], 8);
  }
  if (ln16 == 0) {
#pragma unroll
    for (int e = 0; e < 4; ++e) redS[np][rbase + e] = s[e];
  }
  __syncthreads();
  float rinv[4];
#pragma unroll
  for (int e = 0; e < 4; ++e) rinv[e] = 1.f / (s[e] + redS[np ^ 1][rbase + e]);

  // ---- phase 2: O = P @ Vh (frag-tiled vTile, coalesced) ------------------
  f32x4 o[2] = {};
  {
    const int dp = np;
    const char* pb = (const char*)P;
#pragma unroll
    for (int c = 0; c < 9; ++c) {
      const short8 pf =
          *(const short8*)(pb + (mt * 16 + ln16) * (PST * 2) + c * 64 + quad * 16);
      int j0 = jlo + c * 32 + quad * 8;
      j0 = min(max(j0, 0), L_ - 8);
      const size_t jgbase = ((size_t)b * 256 + (j0 >> 3)) * 1024;
#pragma unroll
      for (int t = 0; t < 2; ++t) {
        const size_t vb = (jgbase + (h * 64 + dp * 32 + t * 16 + ln16)) * 8;
        const short8 vh = *(const short8*)&vTile[vb];
        o[t] = __builtin_amdgcn_mfma_f32_16x16x32_bf16(pf, vh, o[t], 0, 0, 0);
      }
    }
  }

  // ---- epilogue: normalize, LDS bounce, coalesced split-bf16 stores ------
  __syncthreads();
  float* ob = (float*)P;
  {
    const int dp = np;
#pragma unroll
    for (int t = 0; t < 2; ++t)
#pragma unroll
      for (int e = 0; e < 4; ++e)
        ob[(rbase + e) * 68 + dp * 32 + t * 16 + ln16] = o[t][e] * rinv[e];
  }
  __syncthreads();
  {
    const int rr = tid >> 3, ck = tid & 7;
    const float* rp = ob + rr * 68 + ck * 8;
    const float4 f0 = *(const float4*)&rp[0];
    const float4 f1 = *(const float4*)&rp[4];
    float fv[8] = {f0.x, f0.y, f0.z, f0.w, f1.x, f1.y, f1.z, f1.w};
    short8 hh, ll;
#pragma unroll
    for (int i = 0; i < 8; ++i) {
      unsigned short h2, l2;
      split1(fv[i], h2, l2);
      hh[i] = (short)h2; ll[i] = (short)l2;
    }
    const size_t oo = ((size_t)(b * L_ + i0 + rr)) * 1024 + h * 64 + ck * 8;
    *(short8*)&attn_h[oo] = hh;
    *(short8*)&attn_l[oo] = ll;
  }
}

// ---------------------------------------------------------------------------
extern "C" void kernel_launch(void* const* d_in, const int* in_sizes, int n_in,
                              void* d_out, int out_size, void* d_ws, size_t ws_size,
                              hipStream_t stream) {
  const float* x     = (const float*)d_in[0];
  const float* w_qkv = (const float*)d_in[1];
  const float* b_qkv = (const float*)d_in[2];
  const float* w_out = (const float*)d_in[3];
  const float* b_out = (const float*)d_in[4];
  float* out = (float*)d_out;

  const int M = B_ * L_;  // 4096

  // workspace layout (bytes), total 48 MiB:
  //   x_hi @0 (8MiB)     x_lo @8MiB (8MiB)     [dead after V gemm]
  //   wqkvT @16MiB (6MiB)
  //   woutT @22MiB (2MiB)
  //   q_hi  @24MiB (8MiB)   [B*L, 1024]
  //   kT    @32MiB (8MiB)   [b][h][dg8][j2048][8d]
  //   vTile @40MiB (8MiB)   [b][jg256][d1024][8j]
  // aliases over dead x region: attn_hi @0, attn_lo @8MiB
  char* ws = (char*)d_ws;
  unsigned short* x_hi    = (unsigned short*)(ws + 0);
  unsigned short* x_lo    = (unsigned short*)(ws + 8388608);
  unsigned short* wqkvT   = (unsigned short*)(ws + 16777216);
  unsigned short* woutT   = (unsigned short*)(ws + 23068672);
  unsigned short* q_hi    = (unsigned short*)(ws + 25165824);
  unsigned short* kT      = (unsigned short*)(ws + 33554432);
  unsigned short* vTile   = (unsigned short*)(ws + 41943040);
  unsigned short* attn_hi = (unsigned short*)(ws + 0);
  unsigned short* attn_lo = (unsigned short*)(ws + 8388608);

  // 1) fused prep: x split + both weight transposes
  prep<<<8192, 256, 0, stream>>>(x, x_hi, x_lo, w_qkv, wqkvT, w_out, woutT);
  // 2a) Q,K projection (single-product) -> q_hi + kT
  {
    dim3 g(2048 / 128, M / 128);
    gemm_qk<<<g, 256, 0, stream>>>(x_hi, wqkvT, b_qkv, q_hi, kT, 2048, D_);
  }
  // 2b) V projection (2-product, 128x64 tiles) -> vTile
  {
    dim3 g(D_ / 64, M / 128);
    gemm_n64<1><<<g, 256, 0, stream>>>(x_hi, x_lo, wqkvT + (size_t)2048 * D_,
                                       b_qkv + 2048, nullptr, vTile, D_, D_);
  }
  // 3) MFMA banded attention -> attn split bf16 (aliases dead x)
  {
    dim3 g(L_ / TQ, H_, B_);
    attn_mfma<<<g, 256, 0, stream>>>(q_hi, kT, vTile, attn_hi, attn_lo);
  }
  // 4) output projection -> fp32 d_out
  {
    dim3 g(D_ / 64, M / 128);
    gemm_n64<0><<<g, 256, 0, stream>>>(attn_hi, attn_lo, woutT, b_out, out,
                                       nullptr, D_, D_);
  }
}

// Round 13
// 184.701 us; speedup vs baseline: 1.1120x; 1.1120x over previous
//
#include <hip/hip_runtime.h>
#include <math.h>

#define B_    2
#define L_    2048
#define D_    1024
#define H_    16
#define HD_   64
#define HALF_ 128
#define TQ    32          // queries per attention block
#define PST   296         // bf16 P-slab row stride (shorts); 16B-aligned, bank-tiled

typedef __attribute__((ext_vector_type(8))) short short8;
typedef __attribute__((ext_vector_type(4))) float f32x4;

// ---- bf16 helpers (bitwise, RNE) -----------------------------------------
__device__ __forceinline__ unsigned short f2bf(float x) {
  unsigned int u = __float_as_uint(x);
  u = (u + 0x7fffu + ((u >> 16) & 1u)) >> 16;
  return (unsigned short)u;
}

__device__ __forceinline__ void async_cp16(const unsigned short* g, unsigned short* l) {
  __builtin_amdgcn_global_load_lds(
      (const __attribute__((address_space(1))) unsigned int*)g,
      (__attribute__((address_space(3))) unsigned int*)l, 16, 0, 0);
}

// ---------------------------------------------------------------------------
// prep: fused (a) x -> bf16 round (hi only — no consumer uses x_lo anymore),
//       (b) w_qkv transpose+round, (c) w_out transpose+round.
// ---------------------------------------------------------------------------
__device__ __forceinline__ void tr_round32(const float* __restrict__ in,
                                           unsigned short* __restrict__ hi,
                                           int N, int K, int n0, int k0,
                                           float (*t)[33], int tid) {
  {
    const int kl = tid >> 3, nl = (tid & 7) * 4;
    const float4 v = *(const float4*)&in[(size_t)(k0 + kl) * N + n0 + nl];
    t[kl][nl + 0] = v.x; t[kl][nl + 1] = v.y;
    t[kl][nl + 2] = v.z; t[kl][nl + 3] = v.w;
  }
  __syncthreads();
  {
    const int no = tid >> 3, ko = (tid & 7) * 4;
    ushort4 h;
    h.x = f2bf(t[ko + 0][no]);
    h.y = f2bf(t[ko + 1][no]);
    h.z = f2bf(t[ko + 2][no]);
    h.w = f2bf(t[ko + 3][no]);
    *(ushort4*)&hi[(size_t)(n0 + no) * K + k0 + ko] = h;
  }
}

__global__ __launch_bounds__(256) void prep(const float* __restrict__ x,
                                            unsigned short* __restrict__ x_hi,
                                            const float* __restrict__ w_qkv,
                                            unsigned short* __restrict__ wqkvT,
                                            const float* __restrict__ w_out,
                                            unsigned short* __restrict__ woutT) {
  __shared__ float t[32][33];
  const int bx = blockIdx.x, tid = threadIdx.x;
  if (bx < 4096) {
    const int i = (bx * 256 + tid) * 4;
    const float4 a = *(const float4*)&x[i];
    ushort4 h;
    h.x = f2bf(a.x); h.y = f2bf(a.y); h.z = f2bf(a.z); h.w = f2bf(a.w);
    *(ushort4*)&x_hi[i] = h;
  } else if (bx < 7168) {
    const int tb = bx - 4096;  // 96 x 32 tiles
    tr_round32(w_qkv, wqkvT, 3 * D_, D_, (tb % 96) * 32, (tb / 96) * 32, t, tid);
  } else {
    const int tb = bx - 7168;  // 32 x 32 tiles
    tr_round32(w_out, woutT, D_, D_, (tb % 32) * 32, (tb / 32) * 32, t, tid);
  }
}

// ---------------------------------------------------------------------------
// gemm_qk: SINGLE-product bf16 MFMA GEMM for the Q,K projection slice.
// 128x128 tile, BK=32, 16 KB LDS, balanced 4-inst/wave staging, branch-free.
// Epilogue: q -> q_hi[B*L,1024]; k -> kT[b][h][dg8][j2048][8d].
// ---------------------------------------------------------------------------
__global__ __launch_bounds__(256) void gemm_qk(const unsigned short* __restrict__ Ah,
                                               const unsigned short* __restrict__ Bh,
                                               const float* __restrict__ bias,
                                               unsigned short* __restrict__ q_hi,
                                               unsigned short* __restrict__ kT,
                                               int N, int K) {
  __shared__ unsigned short sm[2 * 4096];  // 16 KB: Ah | Bh
  const int tid  = threadIdx.x;
  const int wave = tid >> 6, lane = tid & 63;
  const int m0 = blockIdx.y * 128, n0 = blockIdx.x * 128;
  const int wm = (wave >> 1) * 64, wn = (wave & 1) * 64;
  const int quad = lane >> 4, ln16 = lane & 15;

  const unsigned short* src = (wave < 2) ? Ah : Bh;
  const int baserow = (wave < 2) ? m0 : n0;
  const int io = (wave & 1) * 4;
  size_t goff[4];
#pragma unroll
  for (int i = 0; i < 4; ++i) {
    const int inst = io + i;
    const int r = inst * 16 + (lane >> 2);
    const int q = (lane & 3) ^ ((r >> 1) & 3);
    goff[i] = (size_t)(baserow + r) * K + q * 8;
  }
  unsigned short* dst0 = &sm[(wave >> 1) * 4096 + io * 512];

  int offA[4], offB[4];
#pragma unroll
  for (int t = 0; t < 4; ++t) {
    const int r = wm + t * 16 + ln16;
    offA[t] = r * 64 + ((quad ^ ((r >> 1) & 3)) * 16);
    const int rn = wn + t * 16 + ln16;
    offB[t] = rn * 64 + ((quad ^ ((rn >> 1) & 3)) * 16);
  }

  f32x4 acc[4][4] = {};
  const char* smb = (const char*)sm;

  for (int k0 = 0; k0 < K; k0 += 32) {
#pragma unroll
    for (int i = 0; i < 4; ++i)
      async_cp16(src + goff[i] + k0,
                 (unsigned short*)((char*)dst0 + i * 1024));
    __syncthreads();

    short8 ah[4], bh[4];
#pragma unroll
    for (int t = 0; t < 4; ++t) {
      ah[t] = *(const short8*)(smb + offA[t]);
      bh[t] = *(const short8*)(smb + 8192 + offB[t]);
    }
#pragma unroll
    for (int t = 0; t < 4; ++t)
#pragma unroll
      for (int u = 0; u < 4; ++u)
        acc[t][u] = __builtin_amdgcn_mfma_f32_16x16x32_bf16(ah[t], bh[u], acc[t][u], 0, 0, 0);
    __syncthreads();
  }

#pragma unroll
  for (int u = 0; u < 4; ++u) {
    const int col = n0 + wn + u * 16 + ln16;
    const float bv = bias[col];
    const int slot = col >> 10;   // 0=q, 1=k (wave-uniform per u-tile)
    const int hd   = col & 1023;
    const int hh_  = hd >> 6;
    const int dg   = (hd & 63) >> 3, di = hd & 7;
#pragma unroll
    for (int t = 0; t < 4; ++t) {
      const int row0 = m0 + wm + t * 16 + quad * 4;
      if (slot == 0) {
#pragma unroll
        for (int e = 0; e < 4; ++e)
          q_hi[(size_t)(row0 + e) * 1024 + hd] = f2bf(acc[t][u][e] + bv);
      } else {
#pragma unroll
        for (int e = 0; e < 4; ++e) {
          const int tok = row0 + e;
          const int bb = tok >> 11, j = tok & 2047;
          const size_t o =
              ((((size_t)bb * 16 + hh_) * 8 + dg) * 2048 + j) * 8 + di;
          kT[o] = f2bf(acc[t][u][e] + bv);
        }
      }
    }
  }
}

// ---------------------------------------------------------------------------
// gemm_n64s: SINGLE-product bf16 GEMM, 128x64 tile, BK=32, 12 KB LDS,
// 512 blocks (2/CU). Balanced 3-inst/wave staging (12 insts: Ah 8 + Bh 4),
// branch-free K-loop. EPI=0: fp32 C (out-projection, A = attn_h).
// EPI=1: vTile epilogue (V slice) -> vTile[b][jg256][d1024][8j].
// ---------------------------------------------------------------------------
template <int EPI>
__global__ __launch_bounds__(256) void gemm_n64s(const unsigned short* __restrict__ Ah,
                                                 const unsigned short* __restrict__ Bh,
                                                 const float* __restrict__ bias,
                                                 float* __restrict__ C,
                                                 unsigned short* __restrict__ vTile,
                                                 int N, int K) {
  __shared__ unsigned short sm[6144];  // 12 KB: Ah (8 KB) | Bh (4 KB)
  const int tid  = threadIdx.x;
  const int wave = tid >> 6, lane = tid & 63;
  const int m0 = blockIdx.y * 128, n0 = blockIdx.x * 64;
  const int quad = lane >> 4, ln16 = lane & 15;
  const int wm = wave * 32;

  // staging: 12 insts distributed 3/wave.  g = wave*3+s; g<8 -> Ah, else Bh.
  const unsigned short* sptr[3];
  int dstoff[3];
#pragma unroll
  for (int s = 0; s < 3; ++s) {
    const int g = wave * 3 + s;
    const bool isA = g < 8;
    const unsigned short* base = isA ? Ah : Bh;
    const int r0 = isA ? (m0 + g * 16) : (n0 + (g - 8) * 16);
    const int r = r0 + (lane >> 2);
    const int q = (lane & 3) ^ ((r >> 1) & 3);
    sptr[s] = base + (size_t)r * K + q * 8;
    dstoff[s] = isA ? g * 1024 : 8192 + (g - 8) * 1024;
  }

  int offA[2], offB[4];
#pragma unroll
  for (int t = 0; t < 2; ++t) {
    const int r = wm + t * 16 + ln16;
    offA[t] = r * 64 + ((quad ^ ((r >> 1) & 3)) * 16);
  }
#pragma unroll
  for (int u = 0; u < 4; ++u) {
    const int rn = u * 16 + ln16;
    offB[u] = rn * 64 + ((quad ^ ((rn >> 1) & 3)) * 16);
  }

  f32x4 acc[2][4] = {};
  const char* smb = (const char*)sm;

  for (int k0 = 0; k0 < K; k0 += 32) {
#pragma unroll
    for (int s = 0; s < 3; ++s)
      async_cp16(sptr[s] + k0, (unsigned short*)((char*)sm + dstoff[s]));
    __syncthreads();

    short8 ah[2], bh[4];
#pragma unroll
    for (int t = 0; t < 2; ++t) ah[t] = *(const short8*)(smb + offA[t]);
#pragma unroll
    for (int u = 0; u < 4; ++u) bh[u] = *(const short8*)(smb + 8192 + offB[u]);
#pragma unroll
    for (int t = 0; t < 2; ++t)
#pragma unroll
      for (int u = 0; u < 4; ++u)
        acc[t][u] = __builtin_amdgcn_mfma_f32_16x16x32_bf16(ah[t], bh[u], acc[t][u], 0, 0, 0);
    __syncthreads();
  }

#pragma unroll
  for (int u = 0; u < 4; ++u) {
    const int col = n0 + u * 16 + ln16;
    const float bv = bias[col];
#pragma unroll
    for (int t = 0; t < 2; ++t) {
      const int row0 = m0 + wm + t * 16 + quad * 4;
      if (EPI == 0) {
#pragma unroll
        for (int e = 0; e < 4; ++e)
          C[(size_t)(row0 + e) * N + col] = acc[t][u][e] + bv;
      } else {
        const int bb = row0 >> 11, l0 = row0 & 2047;
        ushort4 vh;
        vh.x = f2bf(acc[t][u][0] + bv);
        vh.y = f2bf(acc[t][u][1] + bv);
        vh.z = f2bf(acc[t][u][2] + bv);
        vh.w = f2bf(acc[t][u][3] + bv);
        const size_t o =
            (((size_t)bb * 256 + (l0 >> 3)) * 1024 + col) * 8 + (l0 & 7);
        *(ushort4*)&vTile[o] = vh;
      }
    }
  }
}

// ---------------------------------------------------------------------------
// MFMA sliding-window attention (r11 structure; epilogue writes attn_h only —
// the out-projection is now single-product, attn_lo is dead).
// ---------------------------------------------------------------------------
__global__ __launch_bounds__(256, 4) void attn_mfma(
    const unsigned short* __restrict__ q_hi,
    const unsigned short* __restrict__ kT,
    const unsigned short* __restrict__ vTile,
    unsigned short* __restrict__ attn_h) {
  __shared__ unsigned short P[TQ * PST];  // 18944 B (epilogue reuses as fp32)
  __shared__ float redS[2][32];

  const int b   = blockIdx.z;
  const int h   = blockIdx.y;
  const int i0  = blockIdx.x * TQ;
  const int tid = threadIdx.x;
  const int wave = tid >> 6, lane = tid & 63;
  const int quad = lane >> 4, ln16 = lane & 15;
  const int mt = wave >> 1, np = wave & 1;
  const int jlo = i0 - HALF_;
  const int rbase = mt * 16 + quad * 4;

  // ---- phase 1: scores -> exp -> P(bf16, unnormalized) + row sums --------
  float s[4] = {0.f, 0.f, 0.f, 0.f};
  {
    const size_t qbase =
        (size_t)(b * L_ + i0 + mt * 16 + ln16) * 1024 + h * 64 + quad * 8;
    const short8 qh0 = *(const short8*)&q_hi[qbase];
    const short8 qh1 = *(const short8*)&q_hi[qbase + 32];

    const size_t kb0 = (((size_t)b * 16 + h) * 8 + quad) * 2048 * 8;
    const size_t kb1 = (((size_t)b * 16 + h) * 8 + quad + 4) * 2048 * 8;

#pragma unroll
    for (int c = 0; c < 9; ++c) {
      const int nt   = np + 2 * c;
      const int jabs = jlo + nt * 16 + ln16;
      const int jcl  = min(max(jabs, 0), L_ - 1);
      const short8 kh0 = *(const short8*)&kT[kb0 + (size_t)jcl * 8];
      const short8 kh1 = *(const short8*)&kT[kb1 + (size_t)jcl * 8];

      f32x4 a = {};
      a = __builtin_amdgcn_mfma_f32_16x16x32_bf16(qh0, kh0, a, 0, 0, 0);
      a = __builtin_amdgcn_mfma_f32_16x16x32_bf16(qh1, kh1, a, 0, 0, 0);

      const int colj = nt * 16 + ln16;
#pragma unroll
      for (int e = 0; e < 4; ++e) {
        const int iabs = i0 + rbase + e;
        const bool ok = (jabs >= 0) && (jabs < L_) && (abs(iabs - jabs) <= HALF_);
        const float ev = ok ? __expf(a[e] * 0.125f) : 0.f;
        s[e] += ev;
        P[(rbase + e) * PST + colj] = f2bf(ev);
      }
    }
  }
#pragma unroll
  for (int e = 0; e < 4; ++e) {
    s[e] += __shfl_xor(s[e], 1);
    s[e] += __shfl_xor(s[e], 2);
    s[e] += __shfl_xor(s[e], 4);
    s[e] += __shfl_xor(s[e], 8);
  }
  if (ln16 == 0) {
#pragma unroll
    for (int e = 0; e < 4; ++e) redS[np][rbase + e] = s[e];
  }
  __syncthreads();
  float rinv[4];
#pragma unroll
  for (int e = 0; e < 4; ++e) rinv[e] = 1.f / (s[e] + redS[np ^ 1][rbase + e]);

  // ---- phase 2: O = P @ Vh (frag-tiled vTile, coalesced) ------------------
  f32x4 o[2] = {};
  {
    const int dp = np;
    const char* pb = (const char*)P;
#pragma unroll
    for (int c = 0; c < 9; ++c) {
      const short8 pf =
          *(const short8*)(pb + (mt * 16 + ln16) * (PST * 2) + c * 64 + quad * 16);
      int j0 = jlo + c * 32 + quad * 8;
      j0 = min(max(j0, 0), L_ - 8);
      const size_t jgbase = ((size_t)b * 256 + (j0 >> 3)) * 1024;
#pragma unroll
      for (int t = 0; t < 2; ++t) {
        const size_t vb = (jgbase + (h * 64 + dp * 32 + t * 16 + ln16)) * 8;
        const short8 vh = *(const short8*)&vTile[vb];
        o[t] = __builtin_amdgcn_mfma_f32_16x16x32_bf16(pf, vh, o[t], 0, 0, 0);
      }
    }
  }

  // ---- epilogue: normalize, LDS bounce, coalesced bf16 stores ------------
  __syncthreads();
  float* ob = (float*)P;
  {
    const int dp = np;
#pragma unroll
    for (int t = 0; t < 2; ++t)
#pragma unroll
      for (int e = 0; e < 4; ++e)
        ob[(rbase + e) * 68 + dp * 32 + t * 16 + ln16] = o[t][e] * rinv[e];
  }
  __syncthreads();
  {
    const int rr = tid >> 3, ck = tid & 7;
    const float* rp = ob + rr * 68 + ck * 8;
    const float4 f0 = *(const float4*)&rp[0];
    const float4 f1 = *(const float4*)&rp[4];
    short8 hh;
    hh[0] = (short)f2bf(f0.x); hh[1] = (short)f2bf(f0.y);
    hh[2] = (short)f2bf(f0.z); hh[3] = (short)f2bf(f0.w);
    hh[4] = (short)f2bf(f1.x); hh[5] = (short)f2bf(f1.y);
    hh[6] = (short)f2bf(f1.z); hh[7] = (short)f2bf(f1.w);
    const size_t oo = ((size_t)(b * L_ + i0 + rr)) * 1024 + h * 64 + ck * 8;
    *(short8*)&attn_h[oo] = hh;
  }
}

// ---------------------------------------------------------------------------
extern "C" void kernel_launch(void* const* d_in, const int* in_sizes, int n_in,
                              void* d_out, int out_size, void* d_ws, size_t ws_size,
                              hipStream_t stream) {
  const float* x     = (const float*)d_in[0];
  const float* w_qkv = (const float*)d_in[1];
  const float* b_qkv = (const float*)d_in[2];
  const float* w_out = (const float*)d_in[3];
  const float* b_out = (const float*)d_in[4];
  float* out = (float*)d_out;

  const int M = B_ * L_;  // 4096

  // workspace layout (bytes), total 48 MiB:
  //   x_hi @0 (8MiB)        [dead after V gemm; attn_h aliases it]
  //   wqkvT @16MiB (6MiB)
  //   woutT @22MiB (2MiB)
  //   q_hi  @24MiB (8MiB)   [B*L, 1024]
  //   kT    @32MiB (8MiB)   [b][h][dg8][j2048][8d]
  //   vTile @40MiB (8MiB)   [b][jg256][d1024][8j]
  char* ws = (char*)d_ws;
  unsigned short* x_hi    = (unsigned short*)(ws + 0);
  unsigned short* wqkvT   = (unsigned short*)(ws + 16777216);
  unsigned short* woutT   = (unsigned short*)(ws + 23068672);
  unsigned short* q_hi    = (unsigned short*)(ws + 25165824);
  unsigned short* kT      = (unsigned short*)(ws + 33554432);
  unsigned short* vTile   = (unsigned short*)(ws + 41943040);
  unsigned short* attn_hi = (unsigned short*)(ws + 0);

  // 1) fused prep: x round + both weight transposes
  prep<<<8192, 256, 0, stream>>>(x, x_hi, w_qkv, wqkvT, w_out, woutT);
  // 2a) Q,K projection (single-product) -> q_hi + kT
  {
    dim3 g(2048 / 128, M / 128);
    gemm_qk<<<g, 256, 0, stream>>>(x_hi, wqkvT, b_qkv, q_hi, kT, 2048, D_);
  }
  // 2b) V projection (single-product, 128x64 tiles) -> vTile
  {
    dim3 g(D_ / 64, M / 128);
    gemm_n64s<1><<<g, 256, 0, stream>>>(x_hi, wqkvT + (size_t)2048 * D_,
                                        b_qkv + 2048, nullptr, vTile, D_, D_);
  }
  // 3) MFMA banded attention -> attn_h bf16 (aliases dead x)
  {
    dim3 g(L_ / TQ, H_, B_);
    attn_mfma<<<g, 256, 0, stream>>>(q_hi, kT, vTile, attn_hi);
  }
  // 4) output projection (single-product) -> fp32 d_out
  {
    dim3 g(D_ / 64, M / 128);
    gemm_n64s<0><<<g, 256, 0, stream>>>(attn_hi, woutT, b_out, out,
                                        nullptr, D_, D_);
  }
}